// Round 1
// baseline (651.755 us; speedup 1.0000x reference)
//
#include <hip/hip_runtime.h>
#include <math.h>

#define NB 8192
#define DIN 1024
#define DOUT 768
#define NE 16

#define BM 128
#define BN 128
#define BK 32
#define KSPLIT 4
#define KCHUNK (DIN / KSPLIT)   // 256
#define NTILES (KCHUNK / BK)    // 8
#define LDT 36                  // LDS row stride in floats (pad: 16B-aligned, conflict-free reads)

#define NSEL 60
#define NCOL 124

#define Y_OFF    0
#define SOFT_OFF 6291456
#define HARD_OFF 6291472
#define SC_OFF   6291488
#define REG_OFF  6422560

__device__ __forceinline__ float smooth_step_f(float t) {
  float p = -2.0f * t * t * t + 1.5f * t + 0.5f;
  p = (t <= -0.5f) ? 0.0f : p;
  p = (t >= 0.5f) ? 1.0f : p;
  return p;
}

// ---------------- K1: G = x @ [sel_w; leaf_w]^T, split-K into 4 partials ----------------
__global__ __launch_bounds__(256) void k1_gemm(
    const float* __restrict__ x, const float* __restrict__ sel_w,
    const float* __restrict__ leaf_w, float* __restrict__ Gp)
{
  __shared__ float xs[BM * LDT];
  __shared__ float wsm[BN * LDT];
  const int t  = threadIdx.x;
  const int b0 = blockIdx.x * BM;
  const int k0 = blockIdx.y * KCHUNK;
  const int rg = t >> 4;   // 0..15 ; rows rg+16i
  const int cg = t & 15;   // 0..15 ; cols cg+16j

  float acc[8][8];
#pragma unroll
  for (int i = 0; i < 8; ++i)
#pragma unroll
    for (int j = 0; j < 8; ++j) acc[i][j] = 0.0f;

  // staging assignment: float4 id f = t + 256*m ; r = f>>3 (0..127), kk0 = (f&7)*4
  int fr[4], fk[4];
#pragma unroll
  for (int m = 0; m < 4; ++m) { int f = t + 256 * m; fr[m] = f >> 3; fk[m] = (f & 7) * 4; }

  float4 px[4], pw[4];
  // load tile 0 into regs
#pragma unroll
  for (int m = 0; m < 4; ++m) {
    int kb = k0 + fk[m];
    px[m] = *(const float4*)(x + (size_t)(b0 + fr[m]) * DIN + kb);
    int c = fr[m];
    if (c < NSEL)      pw[m] = *(const float4*)(sel_w + (size_t)c * DIN + kb);
    else if (c < NCOL) pw[m] = *(const float4*)(leaf_w + (size_t)(c - NSEL) * DIN + kb);
    else               pw[m] = make_float4(0.f, 0.f, 0.f, 0.f);
  }

  for (int kt = 0; kt < NTILES; ++kt) {
    // commit staged regs to LDS
#pragma unroll
    for (int m = 0; m < 4; ++m) {
      *(float4*)(&xs[fr[m] * LDT + fk[m]])  = px[m];
      *(float4*)(&wsm[fr[m] * LDT + fk[m]]) = pw[m];
    }
    __syncthreads();
    // prefetch next tile while computing this one
    if (kt + 1 < NTILES) {
      int kb0 = k0 + (kt + 1) * BK;
#pragma unroll
      for (int m = 0; m < 4; ++m) {
        int kb = kb0 + fk[m];
        px[m] = *(const float4*)(x + (size_t)(b0 + fr[m]) * DIN + kb);
        int c = fr[m];
        if (c < NSEL)      pw[m] = *(const float4*)(sel_w + (size_t)c * DIN + kb);
        else if (c < NCOL) pw[m] = *(const float4*)(leaf_w + (size_t)(c - NSEL) * DIN + kb);
        else               pw[m] = make_float4(0.f, 0.f, 0.f, 0.f);
      }
    }
#pragma unroll 4
    for (int kk = 0; kk < BK; ++kk) {
      float xv[8], wv[8];
#pragma unroll
      for (int i = 0; i < 8; ++i) xv[i] = xs[(rg + 16 * i) * LDT + kk];
#pragma unroll
      for (int j = 0; j < 8; ++j) wv[j] = wsm[(cg + 16 * j) * LDT + kk];
#pragma unroll
      for (int i = 0; i < 8; ++i)
#pragma unroll
        for (int j = 0; j < 8; ++j)
          acc[i][j] = fmaf(xv[i], wv[j], acc[i][j]);
    }
    __syncthreads();
  }

  const int ks = blockIdx.y;
#pragma unroll
  for (int i = 0; i < 8; ++i) {
    int gr = b0 + rg + 16 * i;
#pragma unroll
    for (int j = 0; j < 8; ++j) {
      int c = cg + 16 * j;
      Gp[((size_t)ks * NB + gr) * BN + c] = acc[i][j];
    }
  }
}

// ---------------- K2: per-row tree + softmax + stats ----------------
__global__ __launch_bounds__(256) void k2_rows(
    const float* __restrict__ Gp, const float* __restrict__ leaf_b,
    float* __restrict__ wnorm, float* __restrict__ out)
{
  const int b = blockIdx.x * 256 + threadIdx.x;
  const size_t rb = (size_t)b * BN;

  float s_arr[64];
  float rsum = 0.0f;

#pragma unroll
  for (int k = 0; k < 4; ++k) {
    float gt[15];
#pragma unroll
    for (int n = 0; n < 15; ++n) {
      float v = 0.0f;
#pragma unroll
      for (int s = 0; s < KSPLIT; ++s) v += Gp[(size_t)s * NB * BN + rb + n * 4 + k];
      gt[n] = smooth_step_f(v);
    }
#pragma unroll
    for (int l = 0; l < 16; ++l) {
      float g0 = gt[0];
      float g1 = gt[1 + (l >> 3)];
      float g2 = gt[3 + (l >> 2)];
      float g3 = gt[7 + (l >> 1)];
      float f0 = ((l >> 3) & 1) ? (1.0f - g0) : g0;
      float f1 = ((l >> 2) & 1) ? (1.0f - g1) : g1;
      float f2 = ((l >> 1) & 1) ? (1.0f - g2) : g2;
      float f3 = (l & 1)        ? (1.0f - g3) : g3;
      float p = ((f0 * f1) * f2) * f3;
      // entropy reg term: pc = clip(p, 1e-6); term = -(pc+1e-6)*log(pc+1e-6)
      float pc = fmaxf(p, 1e-6f);
      float lg = logf(pc + 1e-6f);          // when p>=1e-5 this equals log(p+1e-6)
      rsum += -(pc + 1e-6f) * lg;
      float av = 0.0f;
#pragma unroll
      for (int s = 0; s < KSPLIT; ++s) av += Gp[(size_t)s * NB * BN + rb + NSEL + l * 4 + k];
      av += leaf_b[l * 4 + k];
      s_arr[l * 4 + k] = (p < 1e-5f) ? -INFINITY : (av + lg);
    }
  }

  float m = s_arr[0];
#pragma unroll
  for (int i = 1; i < 64; ++i) m = fmaxf(m, s_arr[i]);

  float we[16];
#pragma unroll
  for (int e = 0; e < 16; ++e) we[e] = 0.0f;
  float sum = 0.0f;
#pragma unroll
  for (int e = 0; e < 16; ++e)
#pragma unroll
    for (int k = 0; k < 4; ++k) {
      float wv = expf(s_arr[e * 4 + k] - m);
      sum += wv;
      we[e] += wv;
    }
  float inv = 1.0f / sum;   // w_norm[e] = we[e]/sum (softmax denominators cancel)

  float softp[16], hardp[16];
#pragma unroll
  for (int e = 0; e < 16; ++e) {
    float wn = we[e] * inv;
    softp[e] = wn;
    float sc = (wn < 1e-5f) ? 1.0f : 0.0f;
    hardp[e] = 1.0f - sc;
    wnorm[(size_t)b * NE + e] = wn;
    out[SC_OFF + (size_t)b * NE + e] = sc;
  }

  // wave-reduce partials, one atomic per wave per slot
#pragma unroll
  for (int e = 0; e < 16; ++e) {
    float v = softp[e];
    v += __shfl_down(v, 32, 64); v += __shfl_down(v, 16, 64); v += __shfl_down(v, 8, 64);
    v += __shfl_down(v, 4, 64);  v += __shfl_down(v, 2, 64);  v += __shfl_down(v, 1, 64);
    if ((threadIdx.x & 63) == 0) atomicAdd(&out[SOFT_OFF + e], v * (1.0f / (float)NB));
    float hv = hardp[e];
    hv += __shfl_down(hv, 32, 64); hv += __shfl_down(hv, 16, 64); hv += __shfl_down(hv, 8, 64);
    hv += __shfl_down(hv, 4, 64);  hv += __shfl_down(hv, 2, 64);  hv += __shfl_down(hv, 1, 64);
    if ((threadIdx.x & 63) == 0) atomicAdd(&out[HARD_OFF + e], hv * (1.0f / (float)NB));
  }
  {
    float v = rsum;
    v += __shfl_down(v, 32, 64); v += __shfl_down(v, 16, 64); v += __shfl_down(v, 8, 64);
    v += __shfl_down(v, 4, 64);  v += __shfl_down(v, 2, 64);  v += __shfl_down(v, 1, 64);
    if ((threadIdx.x & 63) == 0) atomicAdd(&out[REG_OFF], v * (0.01f / (float)NB));
  }
}

// ---------------- K3: y_agg[b,d] = sum_e h[b,d,e] * w_norm[b,e] ----------------
__global__ __launch_bounds__(256) void k3_yagg(
    const float* __restrict__ h, const float* __restrict__ wnorm,
    float* __restrict__ out)
{
  const int b = blockIdx.x;
  __shared__ float wl[NE];
  if (threadIdx.x < NE) wl[threadIdx.x] = wnorm[(size_t)b * NE + threadIdx.x];
  __syncthreads();
  float w[NE];
#pragma unroll
  for (int e = 0; e < NE; ++e) w[e] = wl[e];

#pragma unroll
  for (int mm = 0; mm < 3; ++mm) {
    int d = threadIdx.x + 256 * mm;
    const float4* hp = (const float4*)(h + ((size_t)b * DOUT + d) * NE);
    float4 h0 = hp[0], h1 = hp[1], h2 = hp[2], h3 = hp[3];
    float acc;
    acc  = h0.x * w[0]  + h0.y * w[1]  + h0.z * w[2]  + h0.w * w[3];
    acc += h1.x * w[4]  + h1.y * w[5]  + h1.z * w[6]  + h1.w * w[7];
    acc += h2.x * w[8]  + h2.y * w[9]  + h2.z * w[10] + h2.w * w[11];
    acc += h3.x * w[12] + h3.y * w[13] + h3.z * w[14] + h3.w * w[15];
    out[(size_t)b * DOUT + d] = acc;
  }
}

extern "C" void kernel_launch(void* const* d_in, const int* in_sizes, int n_in,
                              void* d_out, int out_size, void* d_ws, size_t ws_size,
                              hipStream_t stream)
{
  const float* h      = (const float*)d_in[0];
  const float* x      = (const float*)d_in[1];
  const float* sel_w  = (const float*)d_in[2];
  const float* leaf_w = (const float*)d_in[3];
  const float* leaf_b = (const float*)d_in[4];
  float* out = (float*)d_out;

  float* wnorm = (float*)d_ws;                    // [8192][16]
  float* Gp    = wnorm + (size_t)NB * NE;         // [4][8192][128]

  // zero the atomically-accumulated outputs (harness poisons d_out with 0xAA)
  hipMemsetAsync(out + SOFT_OFF, 0, 32 * sizeof(float), stream);  // soft+hard (contiguous)
  hipMemsetAsync(out + REG_OFF, 0, sizeof(float), stream);

  k1_gemm<<<dim3(NB / BM, KSPLIT), 256, 0, stream>>>(x, sel_w, leaf_w, Gp);
  k2_rows<<<NB / 256, 256, 0, stream>>>(Gp, leaf_b, wnorm, out);
  k3_yagg<<<NB, 256, 0, stream>>>(h, wnorm, out);
}